// Round 5
// baseline (176.243 us; speedup 1.0000x reference)
//
#include <hip/hip_runtime.h>
#include <math.h>

// RulesLoss: B=1024, T=8192  (fused single-kernel, last-block-reduces)
//   gap1 = max(d - e1[tok], 0)                  (e1 = +INF for non-IV tokens)
//   gap2 = max(fma(dn, -1/3, d), 0) * m2[tok]   (m2 in {0,1}; dn=+INF at row end)
//   g = gap1 + gap2 ; rules[i] = d[i] - g[i] + g[i+1]
//   out = 0.6 * mean( (log((rules+1)/(d+1)))^2 )

constexpr int TT = 8192;
constexpr int BB = 1024;
constexpr int NBLK = 4096;          // 4 blocks/row, 2048 elems/block, 8/thread
constexpr float LOSS_SCALE = 0.6f;

__device__ __forceinline__ float2 tokvals(int t) {
    // membership via two u64 mask halves selected by t&64 (bit-exact per R2)
    const unsigned long long M1L = 0x0000080008000000ULL; // IV low: {43,27}
    const unsigned long long M1H = 0x0400001050000000ULL; // IV high: {94,122,100,92}-64
    const unsigned long long M2L = 0x0000180038000000ULL; // RATIO low: {44,28,29,27,43}
    const unsigned long long M2H = 0x0200000000000000ULL; // RATIO high: {121}-64
    bool hi = (t & 64) != 0;
    int s = t & 63;
    bool in1 = ((hi ? M1H : M1L) >> s) & 1ULL;
    bool in2 = ((hi ? M2H : M2L) >> s) & 1ULL;
    float e1 = in1 ? (hi ? ((t == 122) ? 3.0f : 2.0f) : 5.0f) : INFINITY;
    float m2 = in2 ? 1.0f : 0.0f;
    return make_float2(e1, m2);
}

__global__ __launch_bounds__(256) void rules_fused(const float* __restrict__ dur,
                                                   const int* __restrict__ tok,
                                                   float* __restrict__ partial,
                                                   unsigned* __restrict__ counter,
                                                   float* __restrict__ out) {
    int blk = blockIdx.x;
    int row = blk >> 2, q = blk & 3;
    const float* dr = dur + (size_t)row * TT;
    const int*   tr = tok + (size_t)row * TT;
    int tid = (int)threadIdx.x;
    int i0 = q * 2048 + tid * 8;
    int lane = tid & 63;

    // ---- batched loads (4 dwordx4 in flight before any compute) ----
    float4 da = *reinterpret_cast<const float4*>(dr + i0);
    float4 db = *reinterpret_cast<const float4*>(dr + i0 + 4);
    int4   ta = *reinterpret_cast<const int4*>(tr + i0);
    int4   tb = *reinterpret_cast<const int4*>(tr + i0 + 4);

    // lane-63 halo: next 2 durs + 1 token (masked; overlaps with main loads)
    bool rowend = (q == 3) && (tid == 255);
    float hd8 = 0.0f, hd9 = 0.0f; int ht8 = 0;
    if (lane == 63 && !rowend) {
        float2 hh = *reinterpret_cast<const float2*>(dr + i0 + 8);
        hd8 = hh.x; hd9 = hh.y;
        ht8 = tr[i0 + 8];
    }

    float d[9];
    d[0]=da.x; d[1]=da.y; d[2]=da.z; d[3]=da.w;
    d[4]=db.x; d[5]=db.y; d[6]=db.z; d[7]=db.w;
    int tk[8] = {ta.x, ta.y, ta.z, ta.w, tb.x, tb.y, tb.z, tb.w};

    // d[8] = neighbor's d[0]; lane63 from halo; row end -> +INF (kills g7.gap2)
    float d8s = __shfl_down(d[0], 1, 64);
    d[8] = (lane == 63) ? (rowend ? INFINITY : hd8) : d8s;

    float g[9];
#pragma unroll
    for (int j = 0; j < 8; ++j) {
        float2 lm = tokvals(tk[j]);
        float gap1 = fmaxf(d[j] - lm.x, 0.0f);
        float gap2 = fmaxf(fmaf(d[j+1], -(1.0f/3.0f), d[j]), 0.0f) * lm.y;
        g[j] = gap1 + gap2;
    }

    // g[8] = neighbor's g[0]; lane63 computes from halo; row end -> 0
    float g8s = __shfl_down(g[0], 1, 64);
    if (lane == 63) {
        float2 hlm = tokvals(ht8);
        float gap1 = fmaxf(hd8 - hlm.x, 0.0f);
        float gap2 = fmaxf(fmaf(hd9, -(1.0f/3.0f), hd8), 0.0f) * hlm.y;
        g8s = rowend ? 0.0f : (gap1 + gap2);
    }
    g[8] = g8s;

    float acc = 0.0f;
#pragma unroll
    for (int j = 0; j < 8; ++j) {
        float dp1 = d[j] + 1.0f;
        float num = d[j] - g[j] + g[j + 1] + 1.0f;   // rules + 1
        float c = __logf(__fdividef(num, dp1));      // exactly 0 when both gaps 0
        acc = fmaf(c, c, acc);
    }

    // ---- block reduce ----
#pragma unroll
    for (int off = 32; off; off >>= 1) acc += __shfl_down(acc, off, 64);
    __shared__ float sred[4];
    __shared__ bool amlast;
    int wid = tid >> 6;
    if (lane == 0) sred[wid] = acc;
    __syncthreads();

    // ---- publish partial + ticket; last block reduces ----
    if (tid == 0) {
        float bsum = sred[0] + sred[1] + sred[2] + sred[3];
        __hip_atomic_store(&partial[blk], bsum, __ATOMIC_RELEASE,
                           __HIP_MEMORY_SCOPE_AGENT);
        unsigned ticket = __hip_atomic_fetch_add(counter, 1u, __ATOMIC_ACQ_REL,
                                                 __HIP_MEMORY_SCOPE_AGENT);
        amlast = (ticket == (unsigned)(NBLK - 1));
    }
    __syncthreads();
    if (!amlast) return;

    // all partials are published (release precedes each ticket increment)
    __builtin_amdgcn_fence(__ATOMIC_ACQUIRE, "agent");
    float facc = 0.0f;
    for (int i = tid; i < NBLK; i += 256)
        facc += __hip_atomic_load(&partial[i], __ATOMIC_RELAXED,
                                  __HIP_MEMORY_SCOPE_AGENT);
#pragma unroll
    for (int off = 32; off; off >>= 1) facc += __shfl_down(facc, off, 64);
    __syncthreads();                 // sred reuse
    if (lane == 0) sred[wid] = facc;
    __syncthreads();
    if (tid == 0) {
        float total = sred[0] + sred[1] + sred[2] + sred[3];
        out[0] = LOSS_SCALE * (total / (float)((long long)BB * TT));
    }
}

extern "C" void kernel_launch(void* const* d_in, const int* in_sizes, int n_in,
                              void* d_out, int out_size, void* d_ws, size_t ws_size,
                              hipStream_t stream) {
    const float* dur = (const float*)d_in[0];
    const int*   tok = (const int*)d_in[1];
    unsigned* counter = (unsigned*)d_ws;                       // 4 B at offset 0
    float* partial = (float*)((char*)d_ws + 256);              // 4096 floats
    float* out = (float*)d_out;

    (void)hipMemsetAsync(counter, 0, sizeof(unsigned), stream); // graph-capturable
    rules_fused<<<NBLK, 256, 0, stream>>>(dur, tok, partial, counter, out);
}

// Round 6
// 66.801 us; speedup vs baseline: 2.6383x; 2.6383x over previous
//
#include <hip/hip_runtime.h>
#include <math.h>

// RulesLoss: B=1024, T=8192  (single kernel; per-block relaxed atomicAdd to out)
//   gap1 = max(d - e1[tok], 0)                  (e1 = +INF for non-IV tokens)
//   gap2 = max(fma(dn, -1/3, d), 0) * m2[tok]   (m2 in {0,1}; dn=+INF at row end)
//   g = gap1 + gap2 ; rules[i] = d[i] - g[i] + g[i+1]
//   out = 0.6 * mean( (log((rules+1)/(d+1)))^2 )
// R5 lesson: agent-scope release/acquire per block = per-block L2 wb/inv on
// gfx950 (non-coherent XCD L2s) -> 9x regression. Use relaxed HW f32 atomics.

constexpr int TT = 8192;
constexpr int BB = 1024;
constexpr int NBLK = 4096;          // 4 blocks/row, 2048 elems/block, 8/thread
constexpr float LOSS_SCALE = 0.6f;

__device__ __forceinline__ float2 tokvals(int t) {
    // membership via two u64 mask halves selected by t&64 (bit-exact per R2)
    const unsigned long long M1L = 0x0000080008000000ULL; // IV low: {43,27}
    const unsigned long long M1H = 0x0400001050000000ULL; // IV high: {94,122,100,92}-64
    const unsigned long long M2L = 0x0000180038000000ULL; // RATIO low: {44,28,29,27,43}
    const unsigned long long M2H = 0x0200000000000000ULL; // RATIO high: {121}-64
    bool hi = (t & 64) != 0;
    int s = t & 63;
    bool in1 = ((hi ? M1H : M1L) >> s) & 1ULL;
    bool in2 = ((hi ? M2H : M2L) >> s) & 1ULL;
    float e1 = in1 ? (hi ? ((t == 122) ? 3.0f : 2.0f) : 5.0f) : INFINITY;
    float m2 = in2 ? 1.0f : 0.0f;
    return make_float2(e1, m2);
}

__global__ __launch_bounds__(256) void rules_fused(const float* __restrict__ dur,
                                                   const int* __restrict__ tok,
                                                   float* __restrict__ out) {
    int blk = blockIdx.x;
    int row = blk >> 2, q = blk & 3;
    const float* dr = dur + (size_t)row * TT;
    const int*   tr = tok + (size_t)row * TT;
    int tid = (int)threadIdx.x;
    int i0 = q * 2048 + tid * 8;
    int lane = tid & 63;

    // ---- batched loads (4 dwordx4 in flight before any compute) ----
    float4 da = *reinterpret_cast<const float4*>(dr + i0);
    float4 db = *reinterpret_cast<const float4*>(dr + i0 + 4);
    int4   ta = *reinterpret_cast<const int4*>(tr + i0);
    int4   tb = *reinterpret_cast<const int4*>(tr + i0 + 4);

    // lane-63 halo: next 2 durs + 1 token (masked; overlaps with main loads)
    bool rowend = (q == 3) && (tid == 255);
    float hd8 = 0.0f, hd9 = 0.0f; int ht8 = 0;
    if (lane == 63 && !rowend) {
        float2 hh = *reinterpret_cast<const float2*>(dr + i0 + 8);
        hd8 = hh.x; hd9 = hh.y;
        ht8 = tr[i0 + 8];
    }

    float d[9];
    d[0]=da.x; d[1]=da.y; d[2]=da.z; d[3]=da.w;
    d[4]=db.x; d[5]=db.y; d[6]=db.z; d[7]=db.w;
    int tk[8] = {ta.x, ta.y, ta.z, ta.w, tb.x, tb.y, tb.z, tb.w};

    // d[8] = neighbor's d[0]; lane63 from halo; row end -> +INF (kills g7.gap2)
    float d8s = __shfl_down(d[0], 1, 64);
    d[8] = (lane == 63) ? (rowend ? INFINITY : hd8) : d8s;

    float g[9];
#pragma unroll
    for (int j = 0; j < 8; ++j) {
        float2 lm = tokvals(tk[j]);
        float gap1 = fmaxf(d[j] - lm.x, 0.0f);
        float gap2 = fmaxf(fmaf(d[j+1], -(1.0f/3.0f), d[j]), 0.0f) * lm.y;
        g[j] = gap1 + gap2;
    }

    // g[8] = neighbor's g[0]; lane63 computes from halo; row end -> 0
    float g8s = __shfl_down(g[0], 1, 64);
    if (lane == 63) {
        float2 hlm = tokvals(ht8);
        float gap1 = fmaxf(hd8 - hlm.x, 0.0f);
        float gap2 = fmaxf(fmaf(hd9, -(1.0f/3.0f), hd8), 0.0f) * hlm.y;
        g8s = rowend ? 0.0f : (gap1 + gap2);
    }
    g[8] = g8s;

    float acc = 0.0f;
#pragma unroll
    for (int j = 0; j < 8; ++j) {
        float dp1 = d[j] + 1.0f;
        float num = d[j] - g[j] + g[j + 1] + 1.0f;   // rules + 1
        float c = __logf(__fdividef(num, dp1));      // exactly 0 when both gaps 0
        acc = fmaf(c, c, acc);
    }

    // ---- block reduce ----
#pragma unroll
    for (int off = 32; off; off >>= 1) acc += __shfl_down(acc, off, 64);
    __shared__ float sred[4];
    int wid = tid >> 6;
    if (lane == 0) sred[wid] = acc;
    __syncthreads();

    // one relaxed HW f32 atomic per block, pre-scaled contribution
    if (tid == 0) {
        float bsum = sred[0] + sred[1] + sred[2] + sred[3];
        atomicAdd(out, LOSS_SCALE * (bsum / (float)((long long)BB * TT)));
    }
}

extern "C" void kernel_launch(void* const* d_in, const int* in_sizes, int n_in,
                              void* d_out, int out_size, void* d_ws, size_t ws_size,
                              hipStream_t stream) {
    const float* dur = (const float*)d_in[0];
    const int*   tok = (const int*)d_in[1];
    float* out = (float*)d_out;

    (void)hipMemsetAsync(out, 0, sizeof(float), stream);  // out accumulates from 0
    rules_fused<<<NBLK, 256, 0, stream>>>(dur, tok, out);
}

// Round 7
// 20.391 us; speedup vs baseline: 8.6433x; 3.2761x over previous
//
#include <hip/hip_runtime.h>
#include <math.h>

// RulesLoss: B=1024, T=8192  (two kernels — R5/R6 showed fusion-by-atomics
// costs 40-150 µs on gfx950: same-address device atomics serialize ~11ns each,
// agent-scope acq/rel fences force per-block L2 wb/inv. Plain stores + tiny
// second kernel is the fast structure.)
//   gap1 = max(d - e1[tok], 0)               (e1 = +INF for non-IV tokens)
//   gap2 = (tok in RATIO) ? max(fma(dn,-1/3,d), 0) : 0    (dn=+INF at row end)
//   g = gap1 + gap2 ; rules[i] = d[i] - g[i] + g[i+1]
//   out = 0.6 * mean( (log((rules+1)/(d+1)))^2 )
// LUT packed as one f32: |v| = e1, signbit(v) = RATIO membership ->
// ds_read_b32 gather (half the bank pressure of b64) + 2-VALU decode.

constexpr int TT = 8192;
constexpr int BB = 1024;
constexpr int NBLK = 4096;          // 4 blocks/row, 2048 elems/block, 8/thread
constexpr float LOSS_SCALE = 0.6f;

__global__ __launch_bounds__(256) void rules_partial(const float* __restrict__ dur,
                                                     const int* __restrict__ tok,
                                                     float* __restrict__ partial) {
    int blk = blockIdx.x;
    int row = blk >> 2, q = blk & 3;
    const float* dr = dur + (size_t)row * TT;
    const int*   tr = tok + (size_t)row * TT;
    int tid = (int)threadIdx.x;
    int i0 = q * 2048 + tid * 8;
    int lane = tid & 63;

    // ---- issue all global loads first (in flight during LUT init) ----
    float4 da = *reinterpret_cast<const float4*>(dr + i0);
    float4 db = *reinterpret_cast<const float4*>(dr + i0 + 4);
    int4   ta = *reinterpret_cast<const int4*>(tr + i0);
    int4   tb = *reinterpret_cast<const int4*>(tr + i0 + 4);

    bool rowend = (q == 3) && (tid == 255);
    float hd8 = 0.0f, hd9 = 0.0f; int ht8 = 0;
    if (lane == 63 && !rowend) {
        float2 hh = *reinterpret_cast<const float2*>(dr + i0 + 8);
        hd8 = hh.x; hd9 = hh.y;
        ht8 = tr[i0 + 8];
    }

    // ---- packed LUT: |v| = e1 (INF if not IV), sign = RATIO membership ----
    __shared__ float lut[128];
    if (tid < 128) {
        int t = tid;
        float e1 = INFINITY;
        if (t == 94 || t == 100 || t == 92) e1 = 2.0f;
        else if (t == 122)                  e1 = 3.0f;
        else if (t == 43 || t == 27)        e1 = 5.0f;
        bool m2 = (t == 44 || t == 28 || t == 29 || t == 27 || t == 121 || t == 43);
        lut[t] = m2 ? -e1 : e1;
    }
    __syncthreads();

    float d[9];
    d[0]=da.x; d[1]=da.y; d[2]=da.z; d[3]=da.w;
    d[4]=db.x; d[5]=db.y; d[6]=db.z; d[7]=db.w;
    int tk[8] = {ta.x, ta.y, ta.z, ta.w, tb.x, tb.y, tb.z, tb.w};

    // d[8] = neighbor's d[0]; lane63 from halo; row end -> +INF (kills g7.gap2)
    float d8s = __shfl_down(d[0], 1, 64);
    d[8] = (lane == 63) ? (rowend ? INFINITY : hd8) : d8s;

    float v[8];
#pragma unroll
    for (int j = 0; j < 8; ++j) v[j] = lut[tk[j] & 127];

    float g[9];
#pragma unroll
    for (int j = 0; j < 8; ++j) {
        float gap1 = fmaxf(d[j] - fabsf(v[j]), 0.0f);           // |v| free modifier
        float gap2 = (v[j] < 0.0f)                               // RATIO member
                   ? fmaxf(fmaf(d[j+1], -(1.0f/3.0f), d[j]), 0.0f) : 0.0f;
        g[j] = gap1 + gap2;
    }

    // g[8] = neighbor's g[0]; lane63 computes from halo; row end -> 0
    float g8s = __shfl_down(g[0], 1, 64);
    if (lane == 63) {
        float hv = lut[ht8 & 127];
        float gap1 = fmaxf(hd8 - fabsf(hv), 0.0f);
        float gap2 = (hv < 0.0f)
                   ? fmaxf(fmaf(hd9, -(1.0f/3.0f), hd8), 0.0f) : 0.0f;
        g8s = rowend ? 0.0f : (gap1 + gap2);
    }
    g[8] = g8s;

    float acc = 0.0f;
#pragma unroll
    for (int j = 0; j < 8; ++j) {
        float dp1 = d[j] + 1.0f;
        float num = d[j] - g[j] + g[j + 1] + 1.0f;   // rules + 1
        float c = __logf(__fdividef(num, dp1));      // exactly 0 when both gaps 0
        acc = fmaf(c, c, acc);
    }

    // wave + block reduce, plain store (no atomics)
#pragma unroll
    for (int off = 32; off; off >>= 1) acc += __shfl_down(acc, off, 64);
    __shared__ float sred[4];
    int wid = tid >> 6;
    if (lane == 0) sred[wid] = acc;
    __syncthreads();
    if (tid == 0) partial[blk] = sred[0] + sred[1] + sred[2] + sred[3];
}

__global__ __launch_bounds__(1024) void rules_final(const float* __restrict__ partial,
                                                    float* __restrict__ out) {
    float acc = 0.0f;
    for (int i = (int)threadIdx.x; i < NBLK; i += 1024) acc += partial[i];
#pragma unroll
    for (int off = 32; off; off >>= 1) acc += __shfl_down(acc, off, 64);
    __shared__ float sred[16];
    int lane = threadIdx.x & 63, wid = threadIdx.x >> 6;
    if (lane == 0) sred[wid] = acc;
    __syncthreads();
    if (threadIdx.x == 0) {
        float total = 0.0f;
#pragma unroll
        for (int w = 0; w < 16; ++w) total += sred[w];
        out[0] = LOSS_SCALE * (total / (float)((long long)BB * TT));
    }
}

extern "C" void kernel_launch(void* const* d_in, const int* in_sizes, int n_in,
                              void* d_out, int out_size, void* d_ws, size_t ws_size,
                              hipStream_t stream) {
    const float* dur = (const float*)d_in[0];
    const int*   tok = (const int*)d_in[1];
    float* partial = (float*)d_ws;          // 4096 floats, fully rewritten each call
    float* out = (float*)d_out;

    rules_partial<<<NBLK, 256, 0, stream>>>(dur, tok, partial);
    rules_final<<<1, 1024, 0, stream>>>(partial, out);
}

// Round 8
// 20.048 us; speedup vs baseline: 8.7911x; 1.0171x over previous
//
#include <hip/hip_runtime.h>
#include <math.h>

// RulesLoss: B=1024, T=8192  (two kernels; R5/R6 proved atomics/fence fusion
// costs 40-150us on gfx950 — non-coherent XCD L2s. Plain stores + tiny finisher.)
//   gap1 = max(d - e1[tok], 0)               (e1 = +INF for non-IV tokens)
//   gap2 = (tok in RATIO) ? max(fma(dn,-1/3,d), 0) : 0    (dn=+INF at row end)
//   g = gap1 + gap2 ; rules[i] = d[i] - g[i] + g[i+1]
//   out = 0.6 * mean( (log((rules+1)/(d+1)))^2 )
// R8: 16 elems/thread, 8 dwordx4 (128 B) in flight per thread -> 2x MLP.

constexpr int TT = 8192;
constexpr int BB = 1024;
constexpr int NBLK = 2048;          // 2 blocks/row, 4096 elems/block, 16/thread
constexpr float LOSS_SCALE = 0.6f;

__global__ __launch_bounds__(256) void rules_partial(const float* __restrict__ dur,
                                                     const int* __restrict__ tok,
                                                     float* __restrict__ partial) {
    int blk = blockIdx.x;
    int row = blk >> 1, q = blk & 1;
    const float* dr = dur + (size_t)row * TT;
    const int*   tr = tok + (size_t)row * TT;
    int tid = (int)threadIdx.x;
    int i0 = q * 4096 + tid * 16;
    int lane = tid & 63;

    // ---- issue all 8 main loads up front (128 B in flight/thread) ----
    float4 dl0 = *reinterpret_cast<const float4*>(dr + i0);
    float4 dl1 = *reinterpret_cast<const float4*>(dr + i0 + 4);
    float4 dl2 = *reinterpret_cast<const float4*>(dr + i0 + 8);
    float4 dl3 = *reinterpret_cast<const float4*>(dr + i0 + 12);
    int4   tl0 = *reinterpret_cast<const int4*>(tr + i0);
    int4   tl1 = *reinterpret_cast<const int4*>(tr + i0 + 4);
    int4   tl2 = *reinterpret_cast<const int4*>(tr + i0 + 8);
    int4   tl3 = *reinterpret_cast<const int4*>(tr + i0 + 12);

    bool rowend = (q == 1) && (tid == 255);
    float hd16 = 0.0f, hd17 = 0.0f; int ht16 = 0;
    if (lane == 63 && !rowend) {
        float2 hh = *reinterpret_cast<const float2*>(dr + i0 + 16);
        hd16 = hh.x; hd17 = hh.y;
        ht16 = tr[i0 + 16];
    }

    // ---- packed LUT: |v| = e1 (INF if not IV), sign = RATIO membership ----
    __shared__ float lut[128];
    if (tid < 128) {
        int t = tid;
        float e1 = INFINITY;
        if (t == 94 || t == 100 || t == 92) e1 = 2.0f;
        else if (t == 122)                  e1 = 3.0f;
        else if (t == 43 || t == 27)        e1 = 5.0f;
        bool m2 = (t == 44 || t == 28 || t == 29 || t == 27 || t == 121 || t == 43);
        lut[t] = m2 ? -e1 : e1;
    }
    __syncthreads();

    float d[17];
    d[0]=dl0.x;  d[1]=dl0.y;  d[2]=dl0.z;  d[3]=dl0.w;
    d[4]=dl1.x;  d[5]=dl1.y;  d[6]=dl1.z;  d[7]=dl1.w;
    d[8]=dl2.x;  d[9]=dl2.y;  d[10]=dl2.z; d[11]=dl2.w;
    d[12]=dl3.x; d[13]=dl3.y; d[14]=dl3.z; d[15]=dl3.w;
    int tk[16] = {tl0.x, tl0.y, tl0.z, tl0.w, tl1.x, tl1.y, tl1.z, tl1.w,
                  tl2.x, tl2.y, tl2.z, tl2.w, tl3.x, tl3.y, tl3.z, tl3.w};

    // d[16] = neighbor's d[0]; lane63 from halo; row end -> +INF (kills gap2)
    float d16s = __shfl_down(d[0], 1, 64);
    d[16] = (lane == 63) ? (rowend ? INFINITY : hd16) : d16s;

    float g[17];
#pragma unroll
    for (int j = 0; j < 16; ++j) {
        float v = lut[tk[j] & 127];
        float gap1 = fmaxf(d[j] - fabsf(v), 0.0f);              // |v| free modifier
        float gap2 = (v < 0.0f)                                  // RATIO member
                   ? fmaxf(fmaf(d[j+1], -(1.0f/3.0f), d[j]), 0.0f) : 0.0f;
        g[j] = gap1 + gap2;
    }

    // g[16] = neighbor's g[0]; lane63 computes from halo; row end -> 0
    float g16s = __shfl_down(g[0], 1, 64);
    if (lane == 63) {
        float hv = lut[ht16 & 127];
        float gap1 = fmaxf(hd16 - fabsf(hv), 0.0f);
        float gap2 = (hv < 0.0f)
                   ? fmaxf(fmaf(hd17, -(1.0f/3.0f), hd16), 0.0f) : 0.0f;
        g16s = rowend ? 0.0f : (gap1 + gap2);
    }
    g[16] = g16s;

    float acc = 0.0f;
#pragma unroll
    for (int j = 0; j < 16; ++j) {
        float dp1 = d[j] + 1.0f;
        float num = d[j] - g[j] + g[j + 1] + 1.0f;   // rules + 1
        float c = __logf(__fdividef(num, dp1));      // exactly 0 when both gaps 0
        acc = fmaf(c, c, acc);
    }

    // wave + block reduce, plain store (no atomics)
#pragma unroll
    for (int off = 32; off; off >>= 1) acc += __shfl_down(acc, off, 64);
    __shared__ float sred[4];
    int wid = tid >> 6;
    if (lane == 0) sred[wid] = acc;
    __syncthreads();
    if (tid == 0) partial[blk] = sred[0] + sred[1] + sred[2] + sred[3];
}

__global__ __launch_bounds__(1024) void rules_final(const float* __restrict__ partial,
                                                    float* __restrict__ out) {
    float acc = 0.0f;
    for (int i = (int)threadIdx.x; i < NBLK; i += 1024) acc += partial[i];
#pragma unroll
    for (int off = 32; off; off >>= 1) acc += __shfl_down(acc, off, 64);
    __shared__ float sred[16];
    int lane = threadIdx.x & 63, wid = threadIdx.x >> 6;
    if (lane == 0) sred[wid] = acc;
    __syncthreads();
    if (threadIdx.x == 0) {
        float total = 0.0f;
#pragma unroll
        for (int w = 0; w < 16; ++w) total += sred[w];
        out[0] = LOSS_SCALE * (total / (float)((long long)BB * TT));
    }
}

extern "C" void kernel_launch(void* const* d_in, const int* in_sizes, int n_in,
                              void* d_out, int out_size, void* d_ws, size_t ws_size,
                              hipStream_t stream) {
    const float* dur = (const float*)d_in[0];
    const int*   tok = (const int*)d_in[1];
    float* partial = (float*)d_ws;          // 2048 floats, fully rewritten each call
    float* out = (float*)d_out;

    rules_partial<<<NBLK, 256, 0, stream>>>(dur, tok, partial);
    rules_final<<<1, 1024, 0, stream>>>(partial, out);
}